// Round 1
// baseline (14131.300 us; speedup 1.0000x reference)
//
#include <hip/hip_runtime.h>
#include <cmath>

// Problem constants (B=1024 batches, S=200 nodes, E=128, H=8 heads, dh=16)
constexpr int Bn = 1024, Sn = 200, En = 128, Hn = 8, DHn = 16, Tn = 199;
constexpr long long LOGITS_N = (long long)Bn * Tn * Sn;   // 40,755,200
constexpr long long LOGP_OFF = LOGITS_N;                  // [B] log probs
constexpr long long SOL_OFF  = LOGP_OFF + Bn;             // [B][S] solution (as float)

#define NEG_INF (-__builtin_inff())

// ---------------------------------------------------------------------------
// Kernel 1: h_hat[b] = mean_s enc[b,s,:]; q_hat[b] = h_hat[b] @ Wq[0:128,:]
// ---------------------------------------------------------------------------
__global__ __launch_bounds__(128) void hhat_qhat_kernel(
    const float* __restrict__ enc, const float* __restrict__ Wq,
    float* __restrict__ hh, float* __restrict__ qh)
{
  const int b = blockIdx.x, e = threadIdx.x;
  const float* p = enc + (size_t)b * Sn * En + e;
  float s = 0.f;
  for (int i = 0; i < Sn; ++i) s += p[(size_t)i * En];
  float h = s * (1.0f / Sn);
  __shared__ float hl[En];
  hl[e] = h;
  hh[(size_t)b * En + e] = h;
  __syncthreads();
  float a = 0.f;
#pragma unroll 8
  for (int i = 0; i < En; ++i) a += hl[i] * Wq[i * En + e];
  qh[(size_t)b * En + e] = a;
}

// ---------------------------------------------------------------------------
// Kernel 2: projections. 32 rows of enc per block (rows = b*S+s).
//   kh[b][h][s][d] = enc[b,s,:] @ Wk[:, h*16+d]
//   vh[b][h][s][d] = enc[b,s,:] @ Wv[:, h*16+d]
//   kpT[b][e][s]   = enc[b,s,:] @ Wp[:, e]      (transposed for coalesced u-dot)
// ---------------------------------------------------------------------------
__global__ __launch_bounds__(256) void proj_kernel(
    const float* __restrict__ enc,
    const float* __restrict__ Wk, const float* __restrict__ Wv, const float* __restrict__ Wp,
    float* __restrict__ kh, float* __restrict__ vh, float* __restrict__ kpT)
{
  __shared__ float et[32 * En];     // 16 KB tile of enc rows
  __shared__ float wl[En * En];     // 64 KB weight matrix (LDS-cached)
  const int tid = threadIdx.x;
  const size_t r0 = (size_t)blockIdx.x * 32;

  for (int i = tid; i < 32 * En; i += 256) et[i] = enc[r0 * En + i];

  const float* Ws[3] = {Wk, Wv, Wp};
  for (int m = 0; m < 3; ++m) {
    __syncthreads();                       // protect wl before overwrite (and et after load)
    const float* W = Ws[m];
    for (int i = tid; i < En * En; i += 256) wl[i] = W[i];
    __syncthreads();
    const int j = tid & 127, half = tid >> 7;
    for (int rr = 0; rr < 16; ++rr) {
      const int r = rr * 2 + half;
      float a0 = 0.f, a1 = 0.f, a2 = 0.f, a3 = 0.f;
#pragma unroll 8
      for (int e = 0; e < En; e += 4) {
        a0 += et[r * En + e    ] * wl[(e    ) * En + j];
        a1 += et[r * En + e + 1] * wl[(e + 1) * En + j];
        a2 += et[r * En + e + 2] * wl[(e + 2) * En + j];
        a3 += et[r * En + e + 3] * wl[(e + 3) * En + j];
      }
      const float a = (a0 + a1) + (a2 + a3);
      const size_t rg = r0 + r;
      const int b = (int)(rg / Sn), s = (int)(rg - (size_t)b * Sn);
      if (m == 2) {
        kpT[((size_t)b * En + j) * Sn + s] = a;
      } else {
        float* o = m ? vh : kh;
        o[(((size_t)b * Hn + (j >> 4)) * Sn + s) * DHn + (j & 15)] = a;
      }
    }
  }
}

// ---------------------------------------------------------------------------
// Kernel 3: sequential decode, one block per batch element, 199 steps.
// ---------------------------------------------------------------------------
__global__ __launch_bounds__(256) void decode_kernel(
    const float* __restrict__ enc, const float* __restrict__ vl, const float* __restrict__ vf,
    const float* __restrict__ Wq, const float* __restrict__ Wo,
    const float* __restrict__ kh, const float* __restrict__ vh, const float* __restrict__ kpT,
    const float* __restrict__ qh, float* __restrict__ out)
{
  const int b = blockIdx.x, tid = threadIdx.x;
  const int lane = tid & 63, wv = tid >> 6;

  __shared__ float sc[Hn][Sn];       // scores -> attn
  __shared__ float uvals[Sn];        // masked logits
  __shared__ int   smask[Sn];
  __shared__ float qv[En], qf[En], lastv[En], firstv[En], ctxh[En], octx[En], hhq[En];
  __shared__ int   idx_s;
  __shared__ float logp_s;

  if (tid < Sn) smask[tid] = (tid == 0) ? 1 : 0;   // depot masked from t=0
  if (tid < En) {
    lastv[tid]  = vl[tid];
    firstv[tid] = vf[tid];
    hhq[tid]    = qh[(size_t)b * En + tid];
  }
  if (tid == 0) { logp_s = 0.f; out[SOL_OFF + (size_t)b * Sn] = 0.f; }
  __syncthreads();

  for (int t = 0; t < Tn; ++t) {
    // ---- q = h_hat@Wq_top (precomputed) + last@Wq_mid + first@Wq_bot (t<2 only)
    if (tid < En) {
      float al = 0.f;
#pragma unroll 8
      for (int i = 0; i < En; ++i) al += lastv[i] * Wq[(En + i) * En + tid];
      if (t < 2) {
        float af = 0.f;
#pragma unroll 8
        for (int i = 0; i < En; ++i) af += firstv[i] * Wq[(2 * En + i) * En + tid];
        qf[tid] = af;
      }
      qv[tid] = hhq[tid] + al + qf[tid];
    }
    __syncthreads();

    // ---- scores[h][s] = (q_h . k_h[s]) / 4, masked -> -inf
    if (tid < Sn) {
      const bool mk = smask[tid] != 0;
#pragma unroll
      for (int h = 0; h < Hn; ++h) {
        const float4* kr = (const float4*)(kh + (((size_t)b * Hn + h) * Sn + tid) * DHn);
        float4 k0 = kr[0], k1 = kr[1], k2 = kr[2], k3 = kr[3];
        const float* qp = &qv[h * DHn];
        float a = qp[0]*k0.x + qp[1]*k0.y + qp[2]*k0.z + qp[3]*k0.w
                + qp[4]*k1.x + qp[5]*k1.y + qp[6]*k1.z + qp[7]*k1.w
                + qp[8]*k2.x + qp[9]*k2.y + qp[10]*k2.z + qp[11]*k2.w
                + qp[12]*k3.x + qp[13]*k3.y + qp[14]*k3.z + qp[15]*k3.w;
        sc[h][tid] = mk ? NEG_INF : a * 0.25f;
      }
    }
    __syncthreads();

    // ---- softmax per head (wave wv handles heads wv, wv+4)
    for (int h = wv; h < Hn; h += 4) {
      float m = NEG_INF;
      for (int s = lane; s < Sn; s += 64) m = fmaxf(m, sc[h][s]);
#pragma unroll
      for (int off = 32; off; off >>= 1) m = fmaxf(m, __shfl_xor(m, off));
      float sum = 0.f;
      for (int s = lane; s < Sn; s += 64) { float ev = expf(sc[h][s] - m); sc[h][s] = ev; sum += ev; }
#pragma unroll
      for (int off = 32; off; off >>= 1) sum += __shfl_xor(sum, off);
      const float inv = 1.f / sum;
      for (int s = lane; s < Sn; s += 64) sc[h][s] *= inv;
    }
    __syncthreads();

    // ---- ctx[h] = sum_s attn[h][s] * v_h[s] ; 8 groups x 32 lanes (group = head)
    {
      const int g = tid >> 5, i = tid & 31;
      float acc[16];
#pragma unroll
      for (int d = 0; d < 16; ++d) acc[d] = 0.f;
      for (int s = i; s < Sn; s += 32) {
        const float a = sc[g][s];
        const float4* vp = (const float4*)(vh + (((size_t)b * Hn + g) * Sn + s) * DHn);
        float4 v0 = vp[0], v1 = vp[1], v2 = vp[2], v3 = vp[3];
        acc[0]+=a*v0.x; acc[1]+=a*v0.y; acc[2]+=a*v0.z; acc[3]+=a*v0.w;
        acc[4]+=a*v1.x; acc[5]+=a*v1.y; acc[6]+=a*v1.z; acc[7]+=a*v1.w;
        acc[8]+=a*v2.x; acc[9]+=a*v2.y; acc[10]+=a*v2.z; acc[11]+=a*v2.w;
        acc[12]+=a*v3.x; acc[13]+=a*v3.y; acc[14]+=a*v3.z; acc[15]+=a*v3.w;
      }
#pragma unroll
      for (int off = 16; off; off >>= 1) {
#pragma unroll
        for (int d = 0; d < 16; ++d) acc[d] += __shfl_xor(acc[d], off);
      }
      if (i == 0) {
#pragma unroll
        for (int d = 0; d < 16; ++d) ctxh[g * 16 + d] = acc[d];
      }
    }
    __syncthreads();

    // ---- out_ctx = ctx @ Wo
    if (tid < En) {
      float a = 0.f;
#pragma unroll 8
      for (int i = 0; i < En; ++i) a += ctxh[i] * Wo[i * En + tid];
      octx[tid] = a;
    }
    __syncthreads();

    // ---- u[s] = tanh((out_ctx . k_ptr[s]) / sqrt(128)) * 10 ; kpT is [E][S] per b
    if (tid < Sn) {
      float a0 = 0.f, a1 = 0.f, a2 = 0.f, a3 = 0.f;
      const float* kp = kpT + (size_t)b * En * Sn + tid;
#pragma unroll 8
      for (int e = 0; e < En; e += 4) {
        a0 += octx[e    ] * kp[(size_t)(e    ) * Sn];
        a1 += octx[e + 1] * kp[(size_t)(e + 1) * Sn];
        a2 += octx[e + 2] * kp[(size_t)(e + 2) * Sn];
        a3 += octx[e + 3] * kp[(size_t)(e + 3) * Sn];
      }
      const float a = (a0 + a1) + (a2 + a3);
      const float uu = tanhf(a * 0.08838834764831845f) * 10.f;  // 1/sqrt(128)
      out[((size_t)b * Tn + t) * Sn + tid] = uu;                // raw (unmasked) logits
      uvals[tid] = smask[tid] ? NEG_INF : uu;
    }
    __syncthreads();

    // ---- greedy argmax (first-index tie-break) + cross-entropy; wave 0 only
    if (wv == 0) {
      float bv = NEG_INF; int bi = 1 << 30;
      for (int s = lane; s < Sn; s += 64) {
        const float v = uvals[s];
        if (v > bv || (v == bv && s < bi)) { bv = v; bi = s; }
      }
#pragma unroll
      for (int off = 32; off; off >>= 1) {
        const float ov = __shfl_xor(bv, off); const int oi = __shfl_xor(bi, off);
        if (ov > bv || (ov == bv && oi < bi)) { bv = ov; bi = oi; }
      }
      float sum = 0.f;
      for (int s = lane; s < Sn; s += 64) sum += expf(uvals[s] - bv);  // exp(-inf)=0 for masked
#pragma unroll
      for (int off = 32; off; off >>= 1) sum += __shfl_xor(sum, off);
      if (lane == 0) {
        idx_s = bi;
        logp_s += logf(sum);   // ce = logsumexp - u[argmax] = log(sum(exp(u - max)))
        out[SOL_OFF + (size_t)b * Sn + t + 1] = (float)bi;
      }
    }
    __syncthreads();

    // ---- state update
    const int idx = idx_s;
    if (tid < En) {
      const float lv = enc[((size_t)b * Sn + idx) * En + tid];
      lastv[tid] = lv;
      if (t == 0) firstv[tid] = lv;
    }
    if (tid == 0) smask[idx] = 1;
    __syncthreads();
  }
  if (tid == 0) out[LOGP_OFF + b] = logp_s;
}

// ---------------------------------------------------------------------------
extern "C" void kernel_launch(void* const* d_in, const int* in_sizes, int n_in,
                              void* d_out, int out_size, void* d_ws, size_t ws_size,
                              hipStream_t stream)
{
  const float* enc = (const float*)d_in[0];
  // d_in[1] demands, d_in[2] capacities: unused by the forward pass
  const float* vl  = (const float*)d_in[3];
  const float* vf  = (const float*)d_in[4];
  const float* Wq  = (const float*)d_in[5];
  const float* Wk  = (const float*)d_in[6];
  const float* Wv  = (const float*)d_in[7];
  const float* Wo  = (const float*)d_in[8];
  const float* Wp  = (const float*)d_in[9];
  float* out = (float*)d_out;

  float* ws  = (float*)d_ws;
  float* kh  = ws;                                      // [B][H][S][16]
  float* vh  = kh  + (size_t)Bn * Hn * Sn * DHn;        // [B][H][S][16]
  float* kpT = vh  + (size_t)Bn * Hn * Sn * DHn;        // [B][E][S]
  float* hh  = kpT + (size_t)Bn * En * Sn;              // [B][E]
  float* qh  = hh  + (size_t)Bn * En;                   // [B][E]

  hipLaunchKernelGGL(hhat_qhat_kernel, dim3(Bn), dim3(En), 0, stream, enc, Wq, hh, qh);
  hipLaunchKernelGGL(proj_kernel, dim3((Bn * Sn) / 32), dim3(256), 0, stream,
                     enc, Wk, Wv, Wp, kh, vh, kpT);
  hipLaunchKernelGGL(decode_kernel, dim3(Bn), dim3(256), 0, stream,
                     enc, vl, vf, Wq, Wo, kh, vh, kpT, qh, out);
}